// Round 1
// baseline (3976.748 us; speedup 1.0000x reference)
//
#include <hip/hip_runtime.h>

// CrossConv2d: out = relu(BN(conv3x3(concat(u_bcast, v))) + concat(u_bcast, v))
// u: (4,1,64,128,128) f32, v: (4,8,64,128,128) f32, w: (128,128,3,3) OIHW f32
// out: (4,1,8,128,128,128) f32  == (n=32, c=128, h=128, w=128)

#define EPS 1e-5f

constexpr int Bn = 4, Sn = 8, C1 = 64, CC = 128, H = 128, W = 128;
constexpr int NB = Bn * Sn;          // 32
constexpr int TS = 16;               // spatial tile (16x16 = 256 threads)
constexpr int HALO = TS + 2;         // 18
constexpr int CI_CHUNK = 8;          // input channels staged per LDS pass
constexpr int CO_PER_BLOCK = 16;     // accumulators per thread

__global__ __launch_bounds__(256, 4)
void crossconv_kernel(const float* __restrict__ u,
                      const float* __restrict__ v,
                      const float* __restrict__ wgt,
                      const float* __restrict__ gamma,
                      const float* __restrict__ beta,
                      const float* __restrict__ mean,
                      const float* __restrict__ var,
                      float* __restrict__ out) {
    __shared__ float smem[CI_CHUNK][HALO][HALO];

    const int tid = threadIdx.x;
    const int tx = tid & 15;
    const int ty = tid >> 4;
    const int w0 = blockIdx.x * TS;
    const int h0 = blockIdx.y * TS;
    const int z  = blockIdx.z;            // n * (CC/CO_PER_BLOCK) + co_group
    const int n  = z >> 3;                // CC/CO_PER_BLOCK == 8 groups
    const int co0 = (z & 7) * CO_PER_BLOCK;
    const int b = n >> 3;                 // n / Sn
    // channels 0..63 come from u[b,0,ci], channels 64..127 from v[b,s,ci-64]
    const float* __restrict__ xy_lo = u + (size_t)b * C1 * (H * W);
    const float* __restrict__ xy_hi = v + (size_t)n * C1 * (H * W);

    float acc[CO_PER_BLOCK];
#pragma unroll
    for (int r = 0; r < CO_PER_BLOCK; ++r) acc[r] = 0.f;

    for (int ci0 = 0; ci0 < CC; ci0 += CI_CHUNK) {
        // ---- stage [CI_CHUNK][18][18] input tile with zero padding ----
        for (int e = tid; e < CI_CHUNK * HALO * HALO; e += 256) {
            int ci_l = e / (HALO * HALO);
            int pos  = e - ci_l * (HALO * HALO);
            int rr = pos / HALO;
            int cc = pos - rr * HALO;
            int gh = h0 + rr - 1;
            int gw = w0 + cc - 1;
            int ci = ci0 + ci_l;
            float val = 0.f;
            if ((unsigned)gh < (unsigned)H && (unsigned)gw < (unsigned)W) {
                const float* base = (ci < C1)
                    ? (xy_lo + (size_t)ci * (H * W))
                    : (xy_hi + (size_t)(ci - C1) * (H * W));
                val = base[gh * W + gw];
            }
            smem[ci_l][rr][cc] = val;
        }
        __syncthreads();

        // ---- accumulate: 9 LDS reads feed 16*9 FMAs per ci ----
        for (int ci_l = 0; ci_l < CI_CHUNK; ++ci_l) {
            float in[9];
#pragma unroll
            for (int dh = 0; dh < 3; ++dh)
#pragma unroll
                for (int dw = 0; dw < 3; ++dw)
                    in[dh * 3 + dw] = smem[ci_l][ty + dh][tx + dw];
            const int ci = ci0 + ci_l;
            // block-uniform weight address -> scalar loads (SGPR operands)
            const float* __restrict__ wp = wgt + ((size_t)co0 * CC + ci) * 9;
#pragma unroll
            for (int r = 0; r < CO_PER_BLOCK; ++r) {
#pragma unroll
                for (int t = 0; t < 9; ++t) {
                    acc[r] = fmaf(wp[(size_t)r * (CC * 9) + t], in[t], acc[r]);
                }
            }
        }
        __syncthreads();
    }

    // ---- epilogue: BN + skip + ReLU + store ----
    const int h = h0 + ty;
    const int wc = w0 + tx;
#pragma unroll
    for (int r = 0; r < CO_PER_BLOCK; ++r) {
        const int c = co0 + r;
        const float sc = gamma[c] * rsqrtf(var[c] + EPS);
        const float sh = beta[c] - mean[c] * sc;
        const float* base = (c < C1)
            ? (xy_lo + (size_t)c * (H * W))
            : (xy_hi + (size_t)(c - C1) * (H * W));
        const float xyv = base[h * W + wc];
        const float y = fmaf(acc[r], sc, sh) + xyv;
        out[(((size_t)n * CC + c) * H + h) * W + wc] = fmaxf(y, 0.f);
    }
}

extern "C" void kernel_launch(void* const* d_in, const int* in_sizes, int n_in,
                              void* d_out, int out_size, void* d_ws, size_t ws_size,
                              hipStream_t stream) {
    const float* u     = (const float*)d_in[0];
    const float* v     = (const float*)d_in[1];
    const float* wgt   = (const float*)d_in[2];
    const float* gamma = (const float*)d_in[3];
    const float* beta  = (const float*)d_in[4];
    const float* mean  = (const float*)d_in[5];
    const float* var   = (const float*)d_in[6];
    float* out = (float*)d_out;

    dim3 grid(W / TS, H / TS, NB * (CC / CO_PER_BLOCK));  // 8 x 8 x 256
    dim3 block(256);
    crossconv_kernel<<<grid, block, 0, stream>>>(u, v, wgt, gamma, beta, mean, var, out);
}

// Round 2
// 870.259 us; speedup vs baseline: 4.5696x; 4.5696x over previous
//
#include <hip/hip_runtime.h>
#include <hip/hip_bf16.h>

// CrossConv2d via bf16 MFMA implicit GEMM.
// out[n,co,h,w] = relu( BN(conv3x3(xy)) + xy ),  xy = concat(u_bcast, v)
// GEMM view per image n: D[co, pix] = sum_{t=(kh,kw), ci} W[co][ci;t] * X[ci][pix_shift(t)]
// A-operand = weights (M=co), B-operand = shifted input pixels (N=pix), K=ci chunks of 32.
// mfma_f32_16x16x32_bf16: A[m=lane&15][k=(lane>>4)*8+j], B[n=lane&15][k=(lane>>4)*8+j],
//                         D: col(n)=lane&15, row(m)=(lane>>4)*4+reg.

#define EPS 1e-5f

typedef __attribute__((ext_vector_type(8))) short short8;   // 8 bf16 = 4 VGPRs
typedef __attribute__((ext_vector_type(4))) float f32x4;

constexpr int C1 = 64, CC = 128, Hd = 128, Wd = 128;
constexpr int HW = Hd * Wd;          // 16384
constexpr int SP = 18;               // halo tile side (16 + 2)
constexpr int ROW = 40;              // ushorts per spatial point: 32 ci + 8 pad (80B, 16B-aligned)
constexpr int WFRAGS = 9 * 4 * 8;    // (t, ci-chunk, co-frag)

// ---- prep: fp32 OIHW weights -> bf16 A-fragments in ws ----
// frag f = (t*4 + c)*8 + cf ; lane l holds 8 bf16: co = cf*16+(l&15), ci = c*32+(l>>4)*8+j
__global__ void prep_weights(const float* __restrict__ wgt, ushort* __restrict__ wf) {
    int idx = blockIdx.x * 256 + threadIdx.x;          // one thread per (frag, lane)
    if (idx >= WFRAGS * 64) return;
    int l  = idx & 63;
    int f  = idx >> 6;
    int cf = f & 7;
    int c  = (f >> 3) & 3;
    int t  = f >> 5;
    int kh = t / 3, kw = t % 3;
    int co  = cf * 16 + (l & 15);
    int cib = c * 32 + (l >> 4) * 8;
    ushort* dst = wf + (size_t)idx * 8;
#pragma unroll
    for (int j = 0; j < 8; ++j) {
        float x = wgt[(((size_t)co * CC + cib + j) * 3 + kh) * 3 + kw];
        __hip_bfloat16 b = __float2bfloat16(x);
        dst[j] = *(ushort*)&b;
    }
}

// ---- main: one block = one image n, 16x16 pixel tile, full 128 co ----
__global__ __launch_bounds__(256, 2)
void crossconv_mfma(const float* __restrict__ u,
                    const float* __restrict__ v,
                    const ushort* __restrict__ wf,
                    const float* __restrict__ gamma,
                    const float* __restrict__ beta,
                    const float* __restrict__ mean,
                    const float* __restrict__ var,
                    float* __restrict__ out) {
    __shared__ ushort in_s[SP * SP * ROW];   // 25920 B
    __shared__ float s_sc[CC], s_sh[CC];

    const int tid = threadIdx.x;
    const int w0 = blockIdx.x * 16;
    const int h0 = blockIdx.y * 16;
    const int n  = blockIdx.z;
    const int b  = n >> 3;
    const float* __restrict__ ubase = u + (size_t)b * C1 * HW;
    const float* __restrict__ vbase = v + (size_t)n * C1 * HW;

    if (tid < CC) {
        float sc = gamma[tid] * rsqrtf(var[tid] + EPS);
        s_sc[tid] = sc;
        s_sh[tid] = beta[tid] - mean[tid] * sc;
    }

    const int l    = tid & 63;
    const int wid  = tid >> 6;      // wave id: h-rows wid*4 .. wid*4+3
    const int n16  = l & 15;        // pixel w within tile (B col / D col)
    const int kgrp = l >> 4;        // k-group / D row quad

    f32x4 acc[8][4];
#pragma unroll
    for (int cf = 0; cf < 8; ++cf)
#pragma unroll
        for (int pf = 0; pf < 4; ++pf) acc[cf][pf] = (f32x4)0.f;

    for (int c = 0; c < 4; ++c) {            // ci chunks of 32
        __syncthreads();                     // protect previous chunk's readers
        // stage [32 ci][18][18] fp32 -> bf16 LDS, zero-padded halo
        for (int e = tid; e < 32 * SP * SP; e += 256) {
            int ci_l = e / (SP * SP);
            int r    = e - ci_l * (SP * SP);
            int sph  = r / SP;
            int spw  = r - sph * SP;
            int gh = h0 + sph - 1, gw = w0 + spw - 1;
            int ci = c * 32 + ci_l;
            float val = 0.f;
            if ((unsigned)gh < (unsigned)Hd && (unsigned)gw < (unsigned)Wd) {
                const float* base = (ci < C1) ? (ubase + (size_t)ci * HW)
                                              : (vbase + (size_t)(ci - C1) * HW);
                val = base[gh * Wd + gw];
            }
            __hip_bfloat16 bv = __float2bfloat16(val);
            in_s[(sph * SP + spw) * ROW + ci_l] = *(ushort*)&bv;
        }
        __syncthreads();

#pragma unroll
        for (int t = 0; t < 9; ++t) {        // kernel positions (kh,kw)
            const int kh = t / 3, kw = t % 3;
            short8 bfr[4];
#pragma unroll
            for (int pf = 0; pf < 4; ++pf) {
                int sph = wid * 4 + pf + kh;
                int spw = n16 + kw;
                bfr[pf] = *(const short8*)&in_s[(sph * SP + spw) * ROW + kgrp * 8];
            }
            const short8* wp = (const short8*)wf + ((size_t)(t * 4 + c) * 8) * 64 + l;
#pragma unroll
            for (int cf = 0; cf < 8; ++cf) {
                short8 afr = wp[(size_t)cf * 64];   // coalesced 1KB/wave, L1/L2-resident
#pragma unroll
                for (int pf = 0; pf < 4; ++pf)
                    acc[cf][pf] = __builtin_amdgcn_mfma_f32_16x16x32_bf16(
                        afr, bfr[pf], acc[cf][pf], 0, 0, 0);
            }
        }
    }

    // ---- epilogue: BN + fp32 skip + ReLU ----
#pragma unroll
    for (int cf = 0; cf < 8; ++cf) {
#pragma unroll
        for (int pf = 0; pf < 4; ++pf) {
            const int h = h0 + wid * 4 + pf;
            const int w = w0 + n16;
#pragma unroll
            for (int r = 0; r < 4; ++r) {
                const int co = cf * 16 + kgrp * 4 + r;
                const float* base = (co < C1) ? (ubase + (size_t)co * HW)
                                              : (vbase + (size_t)(co - C1) * HW);
                const float x = base[h * Wd + w];
                const float y = fmaf(acc[cf][pf][r], s_sc[co], s_sh[co]) + x;
                out[((size_t)n * CC + co) * HW + h * Wd + w] = fmaxf(y, 0.f);
            }
        }
    }
}

extern "C" void kernel_launch(void* const* d_in, const int* in_sizes, int n_in,
                              void* d_out, int out_size, void* d_ws, size_t ws_size,
                              hipStream_t stream) {
    const float* u     = (const float*)d_in[0];
    const float* v     = (const float*)d_in[1];
    const float* wgt   = (const float*)d_in[2];
    const float* gamma = (const float*)d_in[3];
    const float* beta  = (const float*)d_in[4];
    const float* mean  = (const float*)d_in[5];
    const float* var   = (const float*)d_in[6];
    float* out = (float*)d_out;
    ushort* wf = (ushort*)d_ws;                 // 288 KB of ws for bf16 weight frags

    prep_weights<<<dim3((WFRAGS * 64 + 255) / 256), dim3(256), 0, stream>>>(wgt, wf);
    crossconv_mfma<<<dim3(Wd / 16, Hd / 16, 32), dim3(256), 0, stream>>>(
        u, v, wf, gamma, beta, mean, var, out);
}